// Round 1
// baseline (562.739 us; speedup 1.0000x reference)
//
#include <hip/hip_runtime.h>
#include <stdint.h>

typedef int v4i __attribute__((ext_vector_type(4)));

static constexpr int Mdim = 4096;
static constexpr int Kdim = 4096;   // IN
static constexpr int Ndim = 11008;  // OUT

#define BM 128
#define BN 128
#define BK 64

__device__ __forceinline__ void gload_lds16(const void* gp, void* lp) {
  __builtin_amdgcn_global_load_lds((const __attribute__((address_space(1))) void*)gp,
                                   (__attribute__((address_space(3))) void*)lp,
                                   16, 0, 0);
}

// ---------------- activation static quant + row sums ----------------
// one block per row of x [4096]; 256 threads * 16 elems each
__global__ void k_quant(const float* __restrict__ x, const float* __restrict__ clampv,
                        signed char* __restrict__ qa, int* __restrict__ rowsum) {
  const int row = blockIdx.x;
  const int t = threadIdx.x;
  const float cv = clampv[0];
  const float a_scale = cv / 127.0f;  // matches reference fl(cv/127)
  const float4* xp = (const float4*)(x + (size_t)row * Kdim) + t * 4;
  int s = 0;
  int w[4];
#pragma unroll
  for (int i = 0; i < 4; ++i) {
    float4 f = xp[i];
    float q0 = fminf(fmaxf(rintf(fminf(fmaxf(f.x, -cv), cv) / a_scale), -127.f), 127.f);
    float q1 = fminf(fmaxf(rintf(fminf(fmaxf(f.y, -cv), cv) / a_scale), -127.f), 127.f);
    float q2 = fminf(fmaxf(rintf(fminf(fmaxf(f.z, -cv), cv) / a_scale), -127.f), 127.f);
    float q3 = fminf(fmaxf(rintf(fminf(fmaxf(f.w, -cv), cv) / a_scale), -127.f), 127.f);
    int i0 = (int)q0, i1 = (int)q1, i2 = (int)q2, i3 = (int)q3;
    s += i0 + i1 + i2 + i3;
    w[i] = (i0 & 255) | ((i1 & 255) << 8) | ((i2 & 255) << 16) | ((i3 & 255) << 24);
  }
  ((int4*)(qa + (size_t)row * Kdim))[t] = make_int4(w[0], w[1], w[2], w[3]);

  // reduce row sum: wave64 shuffle then LDS across 4 waves
#pragma unroll
  for (int off = 32; off > 0; off >>= 1) s += __shfl_down(s, off, 64);
  __shared__ int red[4];
  if ((t & 63) == 0) red[t >> 6] = s;
  __syncthreads();
  if (t == 0) rowsum[row] = red[0] + red[1] + red[2] + red[3];
}

// ---------------- int4 unpack: [N][K/2] int32 -> [N][K] int8 ----------------
// hi nibble -> even index, lo nibble -> odd index
__global__ void k_unpack(const int4* __restrict__ qw, uint2* __restrict__ wb) {
  const int idx = blockIdx.x * 256 + threadIdx.x;  // exact grid, no bounds check
  int4 q = qw[idx];
  uint2 r;
  r.x = (unsigned)(((q.x >> 4) & 15) | ((q.x & 15) << 8) |
                   (((q.y >> 4) & 15) << 16) | ((q.y & 15) << 24));
  r.y = (unsigned)(((q.z >> 4) & 15) | ((q.z & 15) << 8) |
                   (((q.w >> 4) & 15) << 16) | ((q.w & 15) << 24));
  wb[idx] = r;
}

// ---------------- int8 GEMM (A [M,K] i8, B [N,K] i8) + fused epilogue ----------------
__global__ __launch_bounds__(256) void k_gemm(
    const signed char* __restrict__ A, const signed char* __restrict__ B,
    const float* __restrict__ scales, const int* __restrict__ qzeros,
    const float* __restrict__ bias, const float* __restrict__ clampv,
    const int* __restrict__ rowsum, float* __restrict__ out) {
  __shared__ signed char As[BM * BK];  // 8 KB, row-major [128][64]
  __shared__ signed char Bs[BN * BK];  // 8 KB
  const int t = threadIdx.x;
  const int lane = t & 63;
  const int wave = t >> 6;
  const int wm = (wave >> 1) * 64;  // 2x2 wave grid, 64x64 per wave
  const int wn = (wave & 1) * 64;
  const int m0 = blockIdx.y * BM;
  const int n0 = blockIdx.x * BN;

  // staging addresses: 4 threads cover one 64B row chunk-of-16 each
  const signed char* gA0 = A + (size_t)(m0 + (t >> 2)) * Kdim + (t & 3) * 16;
  const signed char* gA1 = gA0 + (size_t)64 * Kdim;
  const signed char* gB0 = B + (size_t)(n0 + (t >> 2)) * Kdim + (t & 3) * 16;
  const signed char* gB1 = gB0 + (size_t)64 * Kdim;
  signed char* lA0 = &As[t * 16];
  signed char* lA1 = &As[4096 + t * 16];
  signed char* lB0 = &Bs[t * 16];
  signed char* lB1 = &Bs[4096 + t * 16];

  v4i acc[4][4] = {};
  const int col = lane & 15;
  const int kb = (lane >> 4) * 16;  // K sub-block within BK=64

  for (int k0 = 0; k0 < Kdim; k0 += BK) {
    gload_lds16(gA0 + k0, lA0);
    gload_lds16(gA1 + k0, lA1);
    gload_lds16(gB0 + k0, lB0);
    gload_lds16(gB1 + k0, lB1);
    __syncthreads();  // compiler emits vmcnt(0) drain before barrier

    v4i av[4], bv[4];
#pragma unroll
    for (int i = 0; i < 4; ++i)
      av[i] = *(const v4i*)&As[(wm + i * 16 + col) * BK + kb];
#pragma unroll
    for (int i = 0; i < 4; ++i)
      bv[i] = *(const v4i*)&Bs[(wn + i * 16 + col) * BK + kb];
#pragma unroll
    for (int i = 0; i < 4; ++i)
#pragma unroll
      for (int j = 0; j < 4; ++j)
        acc[i][j] = __builtin_amdgcn_mfma_i32_16x16x64_i8(av[i], bv[j], acc[i][j], 0, 0, 0);
    __syncthreads();  // LDS reuse guard for next stage
  }

  // epilogue: out = a_scale*scale[n]*(acc - qz[n]*rowsum[m]) + bias[n]
  const float a_scale = clampv[0] / 127.0f;
  const int rq = (lane >> 4) * 4;
  int rs[4][4];
#pragma unroll
  for (int i = 0; i < 4; ++i)
#pragma unroll
    for (int r = 0; r < 4; ++r)
      rs[i][r] = rowsum[m0 + wm + i * 16 + rq + r];
#pragma unroll
  for (int j = 0; j < 4; ++j) {
    const int n = n0 + wn + j * 16 + col;
    const float sn = scales[n] * a_scale;
    const int zn = qzeros[n];
    const float bn = bias[n];
#pragma unroll
    for (int i = 0; i < 4; ++i) {
      const int mb = m0 + wm + i * 16 + rq;
#pragma unroll
      for (int r = 0; r < 4; ++r) {
        const int iv = acc[i][j][r] - zn * rs[i][r];
        out[(size_t)(mb + r) * Ndim + n] = (float)iv * sn + bn;
      }
    }
  }
}

extern "C" void kernel_launch(void* const* d_in, const int* in_sizes, int n_in,
                              void* d_out, int out_size, void* d_ws, size_t ws_size,
                              hipStream_t stream) {
  const float* x  = (const float*)d_in[0];
  const int* qw   = (const int*)d_in[1];
  const int* qz   = (const int*)d_in[2];
  const float* sc = (const float*)d_in[3];
  const float* bi = (const float*)d_in[4];
  const float* cv = (const float*)d_in[5];
  float* out = (float*)d_out;

  // workspace layout: qa[M*K] i8 | wb[N*K] i8 | rowsum[M] i32  (~62 MB)
  signed char* qa = (signed char*)d_ws;
  signed char* wb = qa + (size_t)Mdim * Kdim;
  int* rowsum = (int*)(wb + (size_t)Ndim * Kdim);

  k_quant<<<Mdim, 256, 0, stream>>>(x, cv, qa, rowsum);
  // N*(K/2) int32 = 22,544,384; /4 per thread /256 per block = 22016 blocks exact
  k_unpack<<<(Ndim * (Kdim / 2) / 4) / 256, 256, 0, stream>>>((const int4*)qw, (uint2*)wb);
  k_gemm<<<dim3(Ndim / BN, Mdim / BM), 256, 0, stream>>>(qa, wb, sc, qz, bi, cv, rowsum, out);
}

// Round 2
// 527.600 us; speedup vs baseline: 1.0666x; 1.0666x over previous
//
#include <hip/hip_runtime.h>
#include <stdint.h>

typedef int v4i __attribute__((ext_vector_type(4)));

static constexpr int Mdim = 4096;
static constexpr int Kdim = 4096;   // IN
static constexpr int Ndim = 11008;  // OUT

#define BM 128
#define BN 128
#define BK 128

__device__ __forceinline__ void gload_lds16(const void* gp, void* lp) {
  __builtin_amdgcn_global_load_lds((const __attribute__((address_space(1))) void*)gp,
                                   (__attribute__((address_space(3))) void*)lp,
                                   16, 0, 0);
}

// ---------------- activation static quant + row sums ----------------
__global__ void k_quant(const float* __restrict__ x, const float* __restrict__ clampv,
                        signed char* __restrict__ qa, int* __restrict__ rowsum) {
  const int row = blockIdx.x;
  const int t = threadIdx.x;
  const float cv = clampv[0];
  const float a_scale = cv / 127.0f;
  const float4* xp = (const float4*)(x + (size_t)row * Kdim) + t * 4;
  int s = 0;
  int w[4];
#pragma unroll
  for (int i = 0; i < 4; ++i) {
    float4 f = xp[i];
    float q0 = fminf(fmaxf(rintf(fminf(fmaxf(f.x, -cv), cv) / a_scale), -127.f), 127.f);
    float q1 = fminf(fmaxf(rintf(fminf(fmaxf(f.y, -cv), cv) / a_scale), -127.f), 127.f);
    float q2 = fminf(fmaxf(rintf(fminf(fmaxf(f.z, -cv), cv) / a_scale), -127.f), 127.f);
    float q3 = fminf(fmaxf(rintf(fminf(fmaxf(f.w, -cv), cv) / a_scale), -127.f), 127.f);
    int i0 = (int)q0, i1 = (int)q1, i2 = (int)q2, i3 = (int)q3;
    s += i0 + i1 + i2 + i3;
    w[i] = (i0 & 255) | ((i1 & 255) << 8) | ((i2 & 255) << 16) | ((i3 & 255) << 24);
  }
  ((int4*)(qa + (size_t)row * Kdim))[t] = make_int4(w[0], w[1], w[2], w[3]);
#pragma unroll
  for (int off = 32; off > 0; off >>= 1) s += __shfl_down(s, off, 64);
  __shared__ int red[4];
  if ((t & 63) == 0) red[t >> 6] = s;
  __syncthreads();
  if (t == 0) rowsum[row] = red[0] + red[1] + red[2] + red[3];
}

// ---------------- int4 unpack: [N][K/2] int32 -> [N][K] int8 ----------------
__global__ void k_unpack(const int4* __restrict__ qw, uint2* __restrict__ wb) {
  const int idx = blockIdx.x * 256 + threadIdx.x;
  int4 q = qw[idx];
  uint2 r;
  r.x = (unsigned)(((q.x >> 4) & 15) | ((q.x & 15) << 8) |
                   (((q.y >> 4) & 15) << 16) | ((q.y & 15) << 24));
  r.y = (unsigned)(((q.z >> 4) & 15) | ((q.z & 15) << 8) |
                   (((q.w >> 4) & 15) << 16) | ((q.w & 15) << 24));
  wb[idx] = r;
}

// ---------------- int8 GEMM, BK=128, XOR-swizzled LDS ----------------
// LDS[row][pos] holds global 16B-chunk (pos ^ (row&7)) of that row's 128B K-slab.
__global__ __launch_bounds__(256) void k_gemm(
    const signed char* __restrict__ A, const signed char* __restrict__ B,
    const float* __restrict__ scales, const int* __restrict__ qzeros,
    const float* __restrict__ bias, const float* __restrict__ clampv,
    const int* __restrict__ rowsum, float* __restrict__ out) {
  __shared__ signed char As[BM * BK];  // 16 KB
  __shared__ signed char Bs[BN * BK];  // 16 KB
  const int t = threadIdx.x;
  const int lane = t & 63;
  const int wave = t >> 6;
  const int wm = (wave >> 1) * 64;
  const int wn = (wave & 1) * 64;
  const int m0 = blockIdx.y * BM;
  const int n0 = blockIdx.x * BN;

  // staging: thread t covers row srow=t>>3 (+i*32 per issue), LDS pos t&7.
  // swizzle: fetch global chunk (t&7) ^ (srow&7). (i*32 keeps row&7 invariant)
  const int srow = t >> 3;
  const int schunk = (t & 7) ^ (srow & 7);
  const signed char* gA = A + (size_t)(m0 + srow) * Kdim + schunk * 16;
  const signed char* gB = B + (size_t)(n0 + srow) * Kdim + schunk * 16;

  v4i acc[4][4] = {};
  const int col = lane & 15;
  const int q16 = lane >> 4;   // which 16B chunk within a 64B k-step
  const int c7 = col & 7;      // row&7 for all fragment rows (wm,i*16 are mult of 8)

  for (int k0 = 0; k0 < Kdim; k0 += BK) {
#pragma unroll
    for (int i = 0; i < 4; ++i) {
      gload_lds16(gA + (size_t)i * 32 * Kdim + k0, &As[i * 4096 + t * 16]);
      gload_lds16(gB + (size_t)i * 32 * Kdim + k0, &Bs[i * 4096 + t * 16]);
    }
    __syncthreads();

#pragma unroll
    for (int ks = 0; ks < 2; ++ks) {
      const int pos = ((ks * 4 + q16) ^ c7) * 16;  // swizzled byte offset in row
      v4i av[4], bv[4];
#pragma unroll
      for (int i = 0; i < 4; ++i)
        av[i] = *(const v4i*)&As[(wm + i * 16 + col) * BK + pos];
#pragma unroll
      for (int i = 0; i < 4; ++i)
        bv[i] = *(const v4i*)&Bs[(wn + i * 16 + col) * BK + pos];
#pragma unroll
      for (int i = 0; i < 4; ++i)
#pragma unroll
        for (int j = 0; j < 4; ++j)
          acc[i][j] = __builtin_amdgcn_mfma_i32_16x16x64_i8(av[i], bv[j], acc[i][j], 0, 0, 0);
    }
    __syncthreads();
  }

  // epilogue: out = a_scale*scale[n]*(acc - qz[n]*rowsum[m]) + bias[n]
  const float a_scale = clampv[0] / 127.0f;
  const int rq = (lane >> 4) * 4;
  int rs[4][4];
#pragma unroll
  for (int i = 0; i < 4; ++i)
#pragma unroll
    for (int r = 0; r < 4; ++r)
      rs[i][r] = rowsum[m0 + wm + i * 16 + rq + r];
#pragma unroll
  for (int j = 0; j < 4; ++j) {
    const int n = n0 + wn + j * 16 + col;
    const float sn = scales[n] * a_scale;
    const int zn = qzeros[n];
    const float bn = bias[n];
#pragma unroll
    for (int i = 0; i < 4; ++i) {
      const int mb = m0 + wm + i * 16 + rq;
#pragma unroll
      for (int r = 0; r < 4; ++r) {
        const int iv = acc[i][j][r] - zn * rs[i][r];
        out[(size_t)(mb + r) * Ndim + n] = (float)iv * sn + bn;
      }
    }
  }
}

extern "C" void kernel_launch(void* const* d_in, const int* in_sizes, int n_in,
                              void* d_out, int out_size, void* d_ws, size_t ws_size,
                              hipStream_t stream) {
  const float* x  = (const float*)d_in[0];
  const int* qw   = (const int*)d_in[1];
  const int* qz   = (const int*)d_in[2];
  const float* sc = (const float*)d_in[3];
  const float* bi = (const float*)d_in[4];
  const float* cv = (const float*)d_in[5];
  float* out = (float*)d_out;

  signed char* qa = (signed char*)d_ws;
  signed char* wb = qa + (size_t)Mdim * Kdim;
  int* rowsum = (int*)(wb + (size_t)Ndim * Kdim);

  k_quant<<<Mdim, 256, 0, stream>>>(x, cv, qa, rowsum);
  k_unpack<<<(Ndim * (Kdim / 2) / 4) / 256, 256, 0, stream>>>((const int4*)qw, (uint2*)wb);
  k_gemm<<<dim3(Ndim / BN, Mdim / BM), 256, 0, stream>>>(qa, wb, sc, qz, bi, cv, rowsum, out);
}